// Round 11
// baseline (373.444 us; speedup 1.0000x reference)
//
#include <hip/hip_runtime.h>
#include <hip/hip_bf16.h>
#include <cstdint>

typedef __attribute__((ext_vector_type(8))) short short8;     // 8 bf16 frag (4 VGPRs)
typedef __attribute__((ext_vector_type(16))) float f32x16;    // 32x32 accumulator
typedef unsigned short us;

#define BIN_SHIFT 8
#define BIN_NODES 256
#define CAPB 6144    // per-bin capacity (mean 4092, +32 sigma)
#define EPB 4096     // edges per binA block
#define G1GRID 1024  // gemm1 blocks inside k_bg

__device__ __forceinline__ float bflo(uint32_t u) { return __builtin_bit_cast(float, u << 16); }
__device__ __forceinline__ float bfhi(uint32_t u) { return __builtin_bit_cast(float, u & 0xffff0000u); }

__device__ __forceinline__ us f32_to_bf16_rne(float f) {
  uint32_t u = __builtin_bit_cast(uint32_t, f);
  u += 0x7fffu + ((u >> 16) & 1u);
  return (us)(u >> 16);
}

__device__ __forceinline__ float rdlane_f(float v, int l) {
  return __builtin_bit_cast(float, __builtin_amdgcn_readlane(__builtin_bit_cast(int, v), l));
}

// split f32 into truncated-bf16 hi + bf16 lo (residual); hi+lo ~= f to ~2^-16 rel
__device__ __forceinline__ void split2(float f, us& h, us& l) {
  uint32_t u = __builtin_bit_cast(uint32_t, f);
  h = (us)(u >> 16);
  float fh = __builtin_bit_cast(float, u & 0xffff0000u);
  float r = f - fh;  // exact
  l = (us)(__builtin_bit_cast(uint32_t, r) >> 16);
}

// ---------------- merged weight prep + workspace init (runs FIRST) ----------------------------
__global__ void k_prep(const float* __restrict__ W1, const float* __restrict__ W2,
                       const float* __restrict__ Wp1, const float* __restrict__ Wp2,
                       const float* __restrict__ bp1, const float* __restrict__ bp2,
                       us* __restrict__ Wt1h, us* __restrict__ Wt1l,
                       us* __restrict__ Wt2h, us* __restrict__ Wt2l,
                       us* __restrict__ Wch, us* __restrict__ Wcl, float* __restrict__ bc,
                       int* __restrict__ gcur, int* __restrict__ hzero) {
  int blk = blockIdx.x, tid = threadIdx.x;
  if (blk < 128) {
    const float* W = (blk < 64) ? W1 : W2;
    us* Wh = (blk < 64) ? Wt1h : Wt2h;
    us* Wl = (blk < 64) ? Wt1l : Wt2l;
    int idx = (blk & 63) * 256 + tid;   // 16384
    int k = idx >> 7, n = idx & 127;
    us h, l;
    split2(W[idx], h, l);
    Wh[n * 128 + k] = h;
    Wl[n * 128 + k] = l;
  } else if (blk < 160) {
    int idx = (blk - 128) * 256 + tid;  // 8192
    int k = idx >> 6, j = idx & 63;
    float acc = 0.f;
    for (int t = 0; t < 128; ++t) acc += Wp1[k * 128 + t] * Wp2[t * 64 + j];
    us h, l;
    split2(acc, h, l);
    Wch[j * 128 + k] = h;
    Wcl[j * 128 + k] = l;
  } else {
    // workspace init: gcur[512] = 0, hbuf zero row, bc fold
    gcur[tid] = 0;
    gcur[tid + 256] = 0;
    if (tid < 64) {
      hzero[tid] = 0;  // zero dummy row at hbuf[N]
      float acc = bp2[tid];
      for (int t = 0; t < 128; ++t) acc += bp1[t] * Wp2[t * 64 + tid];
      bc[tid] = acc;
    }
  }
}

// ---------------- merged dispatch: binA (blocks < ablocks) ∥ gemm1-unscaled (rest) -------------
// binA: bin (dst,src) by dst>>8, dense batched appends. Stage holds the FINAL packed u32
//       ((dst&255)<<24 | src); the owning bin of stage[i] is recovered by binary search over
//       base[] (entries are bin-sorted after the scatter), shrinking the LDS union 40->24 KB
//       so both binA and gemm1 blocks get more blocks/CU.
// gemm1: hbuf[row][128] = rne_bf16(x @ W1)  -- NO dis scaling (applied per-edge in gather1).
__global__ __launch_bounds__(256) void k_bg(
    const int* __restrict__ src, const int* __restrict__ dst,
    uint32_t* __restrict__ binbuf, int* __restrict__ gcur, int E, int nbins, int ablocks,
    const float* __restrict__ A, const us* __restrict__ Wh, const us* __restrict__ Wl,
    us* __restrict__ out_bf16, int N, int ntiles) {
  __shared__ int smem[6144];                         // 24 KB union
  int tid = threadIdx.x;
  if ((int)blockIdx.x < ablocks) {
    // ---- binA ----
    uint32_t* stage = (uint32_t*)smem;               // 4096 u32 = 16 KB
    int* cnt   = smem + 4096;                        // 512
    int* base  = smem + 4608;                        // 512
    int* cur   = smem + 5120;                        // 512
    int* gbase = smem + 5632;                        // 512
    int e0 = blockIdx.x * EPB;
    int ne = min(EPB, E - e0);
    if (ne <= 0) return;
    cnt[tid] = 0; cnt[tid + 256] = 0;
    __syncthreads();
    for (int i = tid; i < ne; i += 256) atomicAdd(&cnt[dst[e0 + i] >> BIN_SHIFT], 1);
    __syncthreads();
    // exclusive scan cnt[512] -> base (wave 0, 8 chunks of 64)
    if (tid < 64) {
      int carry = 0;
#pragma unroll
      for (int c = 0; c < 8; ++c) {
        int v = cnt[c * 64 + tid];
        int incl = v;
#pragma unroll
        for (int off = 1; off < 64; off <<= 1) {
          int t = __shfl_up(incl, off, 64);
          if (tid >= off) incl += t;
        }
        base[c * 64 + tid] = carry + incl - v;
        carry += __shfl(incl, 63, 64);
      }
    }
    __syncthreads();
    for (int b = tid; b < nbins; b += 256)
      if (cnt[b] > 0) gbase[b] = atomicAdd(&gcur[b], cnt[b]);
    cur[tid] = base[tid]; cur[tid + 256] = base[tid + 256];
    __syncthreads();
    for (int i = tid; i < ne; i += 256) {
      int d = dst[e0 + i], s = src[e0 + i];
      int p = atomicAdd(&cur[d >> BIN_SHIFT], 1);
      stage[p] = ((unsigned)(d & (BIN_NODES - 1)) << 24) | (unsigned)s;
    }
    __syncthreads();
    for (int i = tid; i < ne; i += 256) {
      uint32_t en = stage[i];
      // binary search: largest b with base[b] <= i  (= owning non-empty bin)
      int b = 0;
#pragma unroll
      for (int step = 256; step; step >>= 1) {
        int nb = b + step;
        if (nb < 512 && base[nb] <= i) b = nb;
      }
      int gi = gbase[b] + (i - base[b]);
      if (gi < CAPB) binbuf[(size_t)b * CAPB + gi] = en;
    }
  } else {
    // ---- gemm1 (unscaled) ----
    us* As = (us*)smem;                              // 32*136 us = 8704 B
    int wave = tid >> 6, lane = tid & 63;
    int n0 = wave * 32;
    int nn = n0 + (lane & 31);
    int khalf = (lane >> 5) * 8;
    int m = lane & 31;

    short8 bh[8], bl[8];
#pragma unroll
    for (int c = 0; c < 8; ++c) {
      bh[c] = *(const short8*)&Wh[nn * 128 + c * 16 + khalf];
      bl[c] = *(const short8*)&Wl[nn * 128 + c * 16 + khalf];
    }

    int t0 = (int)blockIdx.x - ablocks;
    for (int t = t0; t < ntiles; t += G1GRID) {
      int row0 = t * 32;
      __syncthreads();
      for (int j = tid; j < 1024; j += 256) {
        int r = j >> 5, c = j & 31;
        int row = row0 + r;
        float4 v = make_float4(0.f, 0.f, 0.f, 0.f);
        if (row < N) v = *(const float4*)&A[(size_t)row * 128 + c * 4];
        *(ushort4*)&As[r * 136 + c * 4] = make_ushort4(
            f32_to_bf16_rne(v.x), f32_to_bf16_rne(v.y),
            f32_to_bf16_rne(v.z), f32_to_bf16_rne(v.w));
      }
      __syncthreads();

      f32x16 acc = {};
#pragma unroll
      for (int c = 0; c < 8; ++c) {
        short8 ah = *(const short8*)&As[m * 136 + c * 16 + khalf];
        acc = __builtin_amdgcn_mfma_f32_32x32x16_bf16(ah, bh[c], acc, 0, 0, 0);
        acc = __builtin_amdgcn_mfma_f32_32x32x16_bf16(ah, bl[c], acc, 0, 0, 0);
      }

      int colo = n0 + (lane & 31);
      int rbase = row0 + 4 * (lane >> 5);
#pragma unroll
      for (int reg = 0; reg < 16; ++reg) {
        int row = rbase + (reg & 3) + 8 * (reg >> 2);
        if (row < N)
          out_bf16[(size_t)row * 128 + colo] = f32_to_bf16_rne(acc[reg]);
      }
    }
  }
}

// ---------------- pass B: per-bin deg/dis/start + col fill from packed entries ----------------
__global__ __launch_bounds__(256) void k_passB(
    const uint32_t* __restrict__ binbuf, const int* __restrict__ gcur,
    int* __restrict__ deg, float* __restrict__ dis, int* __restrict__ start,
    int* __restrict__ col, int N, int nbins) {
  __shared__ int hist[256], lstart[256], cur[256];
  __shared__ int colstage[CAPB];                     // 24 KB
  __shared__ int binbase_s;
  int b = blockIdx.x, tid = threadIdx.x;
  int node0 = b << BIN_SHIFT;
  int cnt = min(gcur[b], CAPB);
  hist[tid] = 0;
  __syncthreads();
  const uint32_t* bp = binbuf + (size_t)b * CAPB;
  for (int i = tid; i < cnt; i += 256) atomicAdd(&hist[bp[i] >> 24], 1);
  __syncthreads();
  if (tid < 64) {
    // binbase = sum of capped counts of previous bins
    int s = 0;
    for (int i = tid; i < b; i += 64) s += min(gcur[i], CAPB);
#pragma unroll
    for (int off = 32; off; off >>= 1) s += __shfl_xor(s, off, 64);
    if (tid == 0) binbase_s = s;
    // exclusive scan hist[256] -> lstart (4 chunks of 64)
    int carry = 0;
#pragma unroll
    for (int c = 0; c < 4; ++c) {
      int v = hist[c * 64 + tid];
      int incl = v;
#pragma unroll
      for (int off = 1; off < 64; off <<= 1) {
        int t = __shfl_up(incl, off, 64);
        if (tid >= off) incl += t;
      }
      lstart[c * 64 + tid] = carry + incl - v;
      carry += __shfl(incl, 63, 64);
    }
  }
  __syncthreads();
  int binbase = binbase_s;
  {
    int node = node0 + tid;
    if (node < N) {
      int dg = hist[tid];
      deg[node] = dg;
      dis[node] = rsqrtf((float)(dg + 1));
      start[node] = binbase + lstart[tid];
    }
  }
  cur[tid] = lstart[tid];
  __syncthreads();
  for (int i = tid; i < cnt; i += 256) {
    uint32_t en = bp[i];
    int p = atomicAdd(&cur[en >> 24], 1);
    colstage[p] = (int)(en & 0xFFFFFFu);
  }
  __syncthreads();
  for (int i = tid; i < cnt; i += 256) col[binbase + i] = colstage[i];
}

// ---------------- gather layer 1: dis-weighted (h is UNSCALED x@W1) ----------------------------
// acc = sum_e dis[src_e]*h[src_e] + dis[node]*h[node];  act = relu(acc*dis[node] + b1).
// dis[col] preloaded per-lane alongside col; both broadcast via readlane.
__global__ __launch_bounds__(512) void k_gather1(
    const us* __restrict__ h, us* __restrict__ o,
    const int* __restrict__ start, const int* __restrict__ deg,
    const int* __restrict__ col, const float* __restrict__ dis,
    const float* __restrict__ bias, int N) {
  int wave = threadIdx.x >> 6, lane = threadIdx.x & 63;
  int node = blockIdx.x * 8 + wave;
  if (node >= N) return;
  const uint32_t* h1 = (const uint32_t*)h;
  float sc = dis[node];
  uint32_t u = h1[(size_t)node * 64 + lane];     // self row
  float a0 = sc * bflo(u), b0 = sc * bfhi(u);
  float a1 = 0.f, b1 = 0.f, a2 = 0.f, b2 = 0.f, a3 = 0.f, b3 = 0.f;
  float a4 = 0.f, b4 = 0.f, a5 = 0.f, b5 = 0.f, a6 = 0.f, b6 = 0.f, a7 = 0.f, b7 = 0.f;
  int e0 = start[node];
  int dg = deg[node];
  int myc = (lane < dg) ? col[e0 + lane] : N;    // N = zero row (dummy)
  float myd = (lane < dg) ? dis[myc] : 0.f;
  int dgm = min(dg, 64);
  for (int k = 0; k < dgm; k += 8) {
    int c0 = __builtin_amdgcn_readlane(myc, k);
    int c1 = __builtin_amdgcn_readlane(myc, k + 1);
    int c2 = __builtin_amdgcn_readlane(myc, k + 2);
    int c3 = __builtin_amdgcn_readlane(myc, k + 3);
    int c4 = __builtin_amdgcn_readlane(myc, k + 4);
    int c5 = __builtin_amdgcn_readlane(myc, k + 5);
    int c6 = __builtin_amdgcn_readlane(myc, k + 6);
    int c7 = __builtin_amdgcn_readlane(myc, k + 7);
    float d0 = rdlane_f(myd, k),     d1 = rdlane_f(myd, k + 1);
    float d2 = rdlane_f(myd, k + 2), d3 = rdlane_f(myd, k + 3);
    float d4 = rdlane_f(myd, k + 4), d5 = rdlane_f(myd, k + 5);
    float d6 = rdlane_f(myd, k + 6), d7 = rdlane_f(myd, k + 7);
    uint32_t u0 = h1[(size_t)c0 * 64 + lane];
    uint32_t u1 = h1[(size_t)c1 * 64 + lane];
    uint32_t u2 = h1[(size_t)c2 * 64 + lane];
    uint32_t u3 = h1[(size_t)c3 * 64 + lane];
    uint32_t u4 = h1[(size_t)c4 * 64 + lane];
    uint32_t u5 = h1[(size_t)c5 * 64 + lane];
    uint32_t u6 = h1[(size_t)c6 * 64 + lane];
    uint32_t u7 = h1[(size_t)c7 * 64 + lane];
    a0 += d0 * bflo(u0); b0 += d0 * bfhi(u0);
    a1 += d1 * bflo(u1); b1 += d1 * bfhi(u1);
    a2 += d2 * bflo(u2); b2 += d2 * bfhi(u2);
    a3 += d3 * bflo(u3); b3 += d3 * bfhi(u3);
    a4 += d4 * bflo(u4); b4 += d4 * bfhi(u4);
    a5 += d5 * bflo(u5); b5 += d5 * bfhi(u5);
    a6 += d6 * bflo(u6); b6 += d6 * bfhi(u6);
    a7 += d7 * bflo(u7); b7 += d7 * bfhi(u7);
  }
  // extremely rare deg > 64 fallback (Poisson mean 16)
  for (int e = e0 + 64; e < e0 + dg; ++e) {
    int c = col[e];
    float dd = dis[c];
    uint32_t u0 = h1[(size_t)c * 64 + lane];
    a0 += dd * bflo(u0); b0 += dd * bfhi(u0);
  }
  float2 bb = ((const float2*)bias)[lane];
  float ax = ((a0 + a1) + (a2 + a3)) + ((a4 + a5) + (a6 + a7));
  float ay = ((b0 + b1) + (b2 + b3)) + ((b4 + b5) + (b6 + b7));
  float rx = fmaxf(ax * sc + bb.x, 0.f);
  float ry = fmaxf(ay * sc + bb.y, 0.f);
  ((uint32_t*)o)[(size_t)node * 64 + lane] =
      ((uint32_t)f32_to_bf16_rne(ry) << 16) | f32_to_bf16_rne(rx);
}

// ---------------- layer-2 GEMM: hbuf[row][128] = rne_bf16(dis[row] * (act @ W2)) ----------------
__global__ __launch_bounds__(256) void k_gemm2(
    const us* __restrict__ A, const us* __restrict__ Wh,
    const us* __restrict__ Wl, const float* __restrict__ dis,
    us* __restrict__ out_bf16, int N, int ntiles) {
  __shared__ us As[32 * 136];
  int tid = threadIdx.x;
  int wave = tid >> 6, lane = tid & 63;
  int n0 = wave * 32;
  int nn = n0 + (lane & 31);
  int khalf = (lane >> 5) * 8;
  int m = lane & 31;

  short8 bh[8], bl[8];
#pragma unroll
  for (int c = 0; c < 8; ++c) {
    bh[c] = *(const short8*)&Wh[nn * 128 + c * 16 + khalf];
    bl[c] = *(const short8*)&Wl[nn * 128 + c * 16 + khalf];
  }

  for (int t = blockIdx.x; t < ntiles; t += gridDim.x) {
    int row0 = t * 32;
    __syncthreads();
    for (int j = tid; j < 512; j += 256) {
      int r = j >> 4, c = j & 15;
      int row = row0 + r;
      uint4 v = make_uint4(0u, 0u, 0u, 0u);
      if (row < N) v = *(const uint4*)&A[(size_t)row * 128 + c * 8];
      *(uint4*)&As[r * 136 + c * 8] = v;
    }
    __syncthreads();

    f32x16 acc = {};
#pragma unroll
    for (int c = 0; c < 8; ++c) {
      short8 ah = *(const short8*)&As[m * 136 + c * 16 + khalf];
      acc = __builtin_amdgcn_mfma_f32_32x32x16_bf16(ah, bh[c], acc, 0, 0, 0);
      acc = __builtin_amdgcn_mfma_f32_32x32x16_bf16(ah, bl[c], acc, 0, 0, 0);
    }

    int col = n0 + (lane & 31);
    int rbase = row0 + 4 * (lane >> 5);
#pragma unroll
    for (int reg = 0; reg < 16; ++reg) {
      int row = rbase + (reg & 3) + 8 * (reg >> 2);
      if (row < N) {
        float v = acc[reg] * dis[row];
        out_bf16[(size_t)row * 128 + col] = f32_to_bf16_rne(v);
      }
    }
  }
}

// ---------------- gather layer 2: h pre-scaled by dis[src] (unchanged champion path) -----------
__global__ __launch_bounds__(512) void k_gather(
    const us* __restrict__ h, us* __restrict__ o,
    const int* __restrict__ start, const int* __restrict__ deg,
    const int* __restrict__ col, const float* __restrict__ dis,
    const float* __restrict__ bias, int N) {
  int wave = threadIdx.x >> 6, lane = threadIdx.x & 63;
  int node = blockIdx.x * 8 + wave;
  if (node >= N) return;
  const uint32_t* h1 = (const uint32_t*)h;
  uint32_t u = h1[(size_t)node * 64 + lane];     // self row
  float a0 = bflo(u), b0 = bfhi(u);
  float a1 = 0.f, b1 = 0.f, a2 = 0.f, b2 = 0.f, a3 = 0.f, b3 = 0.f;
  float a4 = 0.f, b4 = 0.f, a5 = 0.f, b5 = 0.f, a6 = 0.f, b6 = 0.f, a7 = 0.f, b7 = 0.f;
  int e0 = start[node];
  int dg = deg[node];
  int myc = (lane < dg) ? col[e0 + lane] : N;    // N = zero row (dummy)
  int dgm = min(dg, 64);
  for (int k = 0; k < dgm; k += 8) {
    int c0 = __builtin_amdgcn_readlane(myc, k);
    int c1 = __builtin_amdgcn_readlane(myc, k + 1);
    int c2 = __builtin_amdgcn_readlane(myc, k + 2);
    int c3 = __builtin_amdgcn_readlane(myc, k + 3);
    int c4 = __builtin_amdgcn_readlane(myc, k + 4);
    int c5 = __builtin_amdgcn_readlane(myc, k + 5);
    int c6 = __builtin_amdgcn_readlane(myc, k + 6);
    int c7 = __builtin_amdgcn_readlane(myc, k + 7);
    uint32_t u0 = h1[(size_t)c0 * 64 + lane];
    uint32_t u1 = h1[(size_t)c1 * 64 + lane];
    uint32_t u2 = h1[(size_t)c2 * 64 + lane];
    uint32_t u3 = h1[(size_t)c3 * 64 + lane];
    uint32_t u4 = h1[(size_t)c4 * 64 + lane];
    uint32_t u5 = h1[(size_t)c5 * 64 + lane];
    uint32_t u6 = h1[(size_t)c6 * 64 + lane];
    uint32_t u7 = h1[(size_t)c7 * 64 + lane];
    a0 += bflo(u0); b0 += bfhi(u0);
    a1 += bflo(u1); b1 += bfhi(u1);
    a2 += bflo(u2); b2 += bfhi(u2);
    a3 += bflo(u3); b3 += bfhi(u3);
    a4 += bflo(u4); b4 += bfhi(u4);
    a5 += bflo(u5); b5 += bfhi(u5);
    a6 += bflo(u6); b6 += bfhi(u6);
    a7 += bflo(u7); b7 += bfhi(u7);
  }
  // extremely rare deg > 64 fallback (Poisson mean 16)
  for (int e = e0 + 64; e < e0 + dg; ++e) {
    uint32_t u0 = h1[(size_t)col[e] * 64 + lane];
    a0 += bflo(u0); b0 += bfhi(u0);
  }
  float sc = dis[node];
  float2 bb = ((const float2*)bias)[lane];
  float ax = ((a0 + a1) + (a2 + a3)) + ((a4 + a5) + (a6 + a7));
  float ay = ((b0 + b1) + (b2 + b3)) + ((b4 + b5) + (b6 + b7));
  float rx = fmaxf(ax * sc + bb.x, 0.f);
  float ry = fmaxf(ay * sc + bb.y, 0.f);
  ((uint32_t*)o)[(size_t)node * 64 + lane] =
      ((uint32_t)f32_to_bf16_rne(ry) << 16) | f32_to_bf16_rne(rx);
}

// ---------------- head: out = log_softmax(act @ Wc + bc) via MFMA, fused softmax ----------------
__global__ __launch_bounds__(256) void k_head_mfma(
    const us* __restrict__ act, const us* __restrict__ Wch,
    const us* __restrict__ Wcl, const float* __restrict__ bc,
    float* __restrict__ out, int N) {
  __shared__ us As[64 * 136];
  __shared__ float red[2][2][64];
  int tid = threadIdx.x;
  int wave = tid >> 6, lane = tid & 63;
  int rt = wave >> 1, ct = wave & 1;
  int colj = ct * 32 + (lane & 31);
  int khalf = (lane >> 5) * 8;
  int m = lane & 31;

  short8 bh[8], bl[8];
#pragma unroll
  for (int c = 0; c < 8; ++c) {
    bh[c] = *(const short8*)&Wch[colj * 128 + c * 16 + khalf];
    bl[c] = *(const short8*)&Wcl[colj * 128 + c * 16 + khalf];
  }

  int row0 = blockIdx.x * 64;
  for (int j = tid; j < 1024; j += 256) {
    int r = j >> 4, c = j & 15;
    int row = row0 + r;
    uint4 v = make_uint4(0u, 0u, 0u, 0u);
    if (row < N) v = *(const uint4*)&act[(size_t)row * 128 + c * 8];
    *(uint4*)&As[r * 136 + c * 8] = v;
  }
  __syncthreads();

  f32x16 acc = {};
  int mrow = rt * 32 + m;
#pragma unroll
  for (int c = 0; c < 8; ++c) {
    short8 ah = *(const short8*)&As[mrow * 136 + c * 16 + khalf];
    acc = __builtin_amdgcn_mfma_f32_32x32x16_bf16(ah, bh[c], acc, 0, 0, 0);
    acc = __builtin_amdgcn_mfma_f32_32x32x16_bf16(ah, bl[c], acc, 0, 0, 0);
  }

  float bcv = bc[colj];
  float lg[16], mx[16];
#pragma unroll
  for (int reg = 0; reg < 16; ++reg) {
    lg[reg] = acc[reg] + bcv;
    float v = lg[reg];
#pragma unroll
    for (int off = 16; off > 0; off >>= 1) v = fmaxf(v, __shfl_xor(v, off, 32));
    mx[reg] = v;
  }
  if ((lane & 31) == 0) {
#pragma unroll
    for (int reg = 0; reg < 16; ++reg) {
      int rl = rt * 32 + (reg & 3) + 8 * (reg >> 2) + 4 * (lane >> 5);
      red[0][ct][rl] = mx[reg];
    }
  }
  __syncthreads();

  float ex[16], sm[16];
#pragma unroll
  for (int reg = 0; reg < 16; ++reg) {
    int rl = rt * 32 + (reg & 3) + 8 * (reg >> 2) + 4 * (lane >> 5);
    float rmax = fmaxf(red[0][0][rl], red[0][1][rl]);
    ex[reg] = lg[reg] - rmax;
    float v = expf(ex[reg]);
#pragma unroll
    for (int off = 16; off > 0; off >>= 1) v += __shfl_xor(v, off, 32);
    sm[reg] = v;
  }
  if ((lane & 31) == 0) {
#pragma unroll
    for (int reg = 0; reg < 16; ++reg) {
      int rl = rt * 32 + (reg & 3) + 8 * (reg >> 2) + 4 * (lane >> 5);
      red[1][ct][rl] = sm[reg];
    }
  }
  __syncthreads();

#pragma unroll
  for (int reg = 0; reg < 16; ++reg) {
    int rl = rt * 32 + (reg & 3) + 8 * (reg >> 2) + 4 * (lane >> 5);
    int row = row0 + rl;
    if (row < N) {
      float total = red[1][0][rl] + red[1][1][rl];
      out[(size_t)row * 64 + colj] = ex[reg] - logf(total);
    }
  }
}

extern "C" void kernel_launch(void* const* d_in, const int* in_sizes, int n_in,
                              void* d_out, int out_size, void* d_ws, size_t ws_size,
                              hipStream_t stream) {
  const float* x   = (const float*)d_in[0];
  const int*   ei  = (const int*)d_in[1];
  const float* W1  = (const float*)d_in[2];
  const float* b1  = (const float*)d_in[3];
  const float* W2  = (const float*)d_in[4];
  const float* b2  = (const float*)d_in[5];
  const float* Wp1 = (const float*)d_in[6];
  const float* bp1 = (const float*)d_in[7];
  const float* Wp2 = (const float*)d_in[8];
  const float* bp2 = (const float*)d_in[9];
  float* out = (float*)d_out;

  int N = in_sizes[0] / 128;
  int E = in_sizes[1] / 2;
  const int* src = ei;
  const int* dst = ei + E;
  int nbins = (N + BIN_NODES - 1) >> BIN_SHIFT;

  // workspace layout (int granularity)
  float* dis   = (float*)d_ws;                    // N
  int*   deg   = (int*)(dis + N);                 // N
  int*   start = deg + N;                         // N
  int*   col   = start + N;                       // E
  int*   gcur  = col + ((E + 3) & ~3);            // 512 (zeroed by k_prep)
  us* Wt1h = (us*)(gcur + 512);                   // 16384 each
  us* Wt1l = Wt1h + 16384;
  us* Wt2h = Wt1l + 16384;
  us* Wt2l = Wt2h + 16384;
  us* Wch  = Wt2l + 16384;                        // 8192
  us* Wcl  = Wch + 8192;                          // 8192
  float* bc = (float*)(Wcl + 8192);               // 64 (+pad)
  uint32_t* binbuf = (uint32_t*)(bc + 80);        // nbins*CAPB packed u32 (~9.6 MB)
  us* hbuf = (us*)(binbuf + (size_t)nbins * CAPB);  // (N+1)*128 bf16 (row N = zero, by k_prep)
  us* act  = hbuf + (size_t)(N + 1) * 128;          // N*128 bf16 = 25.6 MB

  int ablocks = (E + EPB - 1) / EPB;
  int ntiles = (N + 31) / 32;
  int agblocks = (N + 7) / 8;
  int hblocks = (N + 63) / 64;

  // prep: weight transform + gcur/zero-row init
  k_prep<<<161, 256, 0, stream>>>(W1, W2, Wp1, Wp2, bp1, bp2,
                                  Wt1h, Wt1l, Wt2h, Wt2l, Wch, Wcl, bc,
                                  gcur, (int*)(hbuf + (size_t)N * 128));
  // merged: binA (edge binning) ∥ gemm1-unscaled (x @ W1)
  k_bg<<<ablocks + G1GRID, 256, 0, stream>>>(src, dst, binbuf, gcur, E, nbins, ablocks,
                                             x, Wt1h, Wt1l, hbuf, N, ntiles);
  k_passB<<<nbins, 256, 0, stream>>>(binbuf, gcur, deg, dis, start, col, N, nbins);

  // layer 1 aggregate (dis-weighted, since hbuf is unscaled)
  k_gather1<<<agblocks, 512, 0, stream>>>(hbuf, act, start, deg, col, dis, b1, N);
  // layer 2
  k_gemm2<<<ntiles < 1024 ? ntiles : 1024, 256, 0, stream>>>(act, Wt2h, Wt2l, dis, hbuf, N, ntiles);
  k_gather<<<agblocks, 512, 0, stream>>>(hbuf, act, start, deg, col, dis, b2, N);
  // folded head (MFMA + fused log_softmax)
  k_head_mfma<<<hblocks, 256, 0, stream>>>(act, Wch, Wcl, bc, out, N);
}

// Round 12
// 368.206 us; speedup vs baseline: 1.0142x; 1.0142x over previous
//
#include <hip/hip_runtime.h>
#include <hip/hip_bf16.h>
#include <cstdint>

typedef __attribute__((ext_vector_type(8))) short short8;     // 8 bf16 frag (4 VGPRs)
typedef __attribute__((ext_vector_type(16))) float f32x16;    // 32x32 accumulator
typedef unsigned short us;

#define BIN_SHIFT 8
#define BIN_NODES 256
#define CAPB 6144    // per-bin capacity (mean 4092, +32 sigma)
#define EPB 4096     // edges per binA block
#define G1GRID 1024  // gemm1 blocks inside k_bg
#define PBLK 97      // prep blocks inside k_bg (64 W2-split + 32 head-fold + 1 init)

__device__ __forceinline__ float bflo(uint32_t u) { return __builtin_bit_cast(float, u << 16); }
__device__ __forceinline__ float bfhi(uint32_t u) { return __builtin_bit_cast(float, u & 0xffff0000u); }

__device__ __forceinline__ us f32_to_bf16_rne(float f) {
  uint32_t u = __builtin_bit_cast(uint32_t, f);
  u += 0x7fffu + ((u >> 16) & 1u);
  return (us)(u >> 16);
}

__device__ __forceinline__ float rdlane_f(float v, int l) {
  return __builtin_bit_cast(float, __builtin_amdgcn_readlane(__builtin_bit_cast(int, v), l));
}

// split f32 into truncated-bf16 hi + bf16 lo (residual); hi+lo ~= f to ~2^-16 rel
__device__ __forceinline__ void split2(float f, us& h, us& l) {
  uint32_t u = __builtin_bit_cast(uint32_t, f);
  h = (us)(u >> 16);
  float fh = __builtin_bit_cast(float, u & 0xffff0000u);
  float r = f - fh;  // exact
  l = (us)(__builtin_bit_cast(uint32_t, r) >> 16);
}

// ---------------- mega-dispatch: prep ∥ binA ∥ gemm1 ------------------------------------------
// blocks [0, PBLK): weight prep (W2 split, head fold, bc+hzero init)  -- outputs consumed only
//                   by LATER dispatches (gemm2/head/gather1), no intra-dispatch race.
// blocks [PBLK, PBLK+ablocks): binA -- bin (dst,src) by dst>>8, packed u32 entries,
//                   bin recovered by binary search over base[] (24 KB LDS union).
// blocks [PBLK+ablocks, ...): gemm1 -- hbuf = rne_bf16(x @ W1), UNSCALED (dis applied in
//                   gather1). W1 fragments self-converted from f32 (64 KB, L2-hot) so no
//                   dependency on a prior weight-prep dispatch.  gcur zeroed by memset.
__global__ __launch_bounds__(256) void k_bg(
    const int* __restrict__ src, const int* __restrict__ dst,
    uint32_t* __restrict__ binbuf, int* __restrict__ gcur, int E, int nbins, int ablocks,
    const float* __restrict__ A, const float* __restrict__ W1,
    us* __restrict__ out_bf16, int N, int ntiles,
    const float* __restrict__ W2, const float* __restrict__ Wp1,
    const float* __restrict__ Wp2, const float* __restrict__ bp1,
    const float* __restrict__ bp2,
    us* __restrict__ Wt2h, us* __restrict__ Wt2l,
    us* __restrict__ Wch, us* __restrict__ Wcl, float* __restrict__ bc,
    int* __restrict__ hzero) {
  __shared__ int smem[6144];                         // 24 KB union
  int tid = threadIdx.x;
  int gb = blockIdx.x;
  if (gb < PBLK) {
    // ---- prep ----
    if (gb < 64) {
      int idx = gb * 256 + tid;   // 16384
      int k = idx >> 7, n = idx & 127;
      us h, l;
      split2(W2[idx], h, l);
      Wt2h[n * 128 + k] = h;
      Wt2l[n * 128 + k] = l;
    } else if (gb < 96) {
      int idx = (gb - 64) * 256 + tid;  // 8192
      int k = idx >> 6, j = idx & 63;
      float acc = 0.f;
      for (int t = 0; t < 128; ++t) acc += Wp1[k * 128 + t] * Wp2[t * 64 + j];
      us h, l;
      split2(acc, h, l);
      Wch[j * 128 + k] = h;
      Wcl[j * 128 + k] = l;
    } else {
      if (tid < 64) {
        hzero[tid] = 0;  // zero dummy row at hbuf[N]
        float acc = bp2[tid];
        for (int t = 0; t < 128; ++t) acc += bp1[t] * Wp2[t * 64 + tid];
        bc[tid] = acc;
      }
    }
    return;
  }
  if (gb < PBLK + ablocks) {
    // ---- binA ----
    uint32_t* stage = (uint32_t*)smem;               // 4096 u32 = 16 KB
    int* cnt   = smem + 4096;                        // 512
    int* base  = smem + 4608;                        // 512
    int* cur   = smem + 5120;                        // 512
    int* gbase = smem + 5632;                        // 512
    int e0 = (gb - PBLK) * EPB;
    int ne = min(EPB, E - e0);
    if (ne <= 0) return;
    cnt[tid] = 0; cnt[tid + 256] = 0;
    __syncthreads();
    for (int i = tid; i < ne; i += 256) atomicAdd(&cnt[dst[e0 + i] >> BIN_SHIFT], 1);
    __syncthreads();
    // exclusive scan cnt[512] -> base (wave 0, 8 chunks of 64)
    if (tid < 64) {
      int carry = 0;
#pragma unroll
      for (int c = 0; c < 8; ++c) {
        int v = cnt[c * 64 + tid];
        int incl = v;
#pragma unroll
        for (int off = 1; off < 64; off <<= 1) {
          int t = __shfl_up(incl, off, 64);
          if (tid >= off) incl += t;
        }
        base[c * 64 + tid] = carry + incl - v;
        carry += __shfl(incl, 63, 64);
      }
    }
    __syncthreads();
    for (int b = tid; b < nbins; b += 256)
      if (cnt[b] > 0) gbase[b] = atomicAdd(&gcur[b], cnt[b]);
    cur[tid] = base[tid]; cur[tid + 256] = base[tid + 256];
    __syncthreads();
    for (int i = tid; i < ne; i += 256) {
      int d = dst[e0 + i], s = src[e0 + i];
      int p = atomicAdd(&cur[d >> BIN_SHIFT], 1);
      stage[p] = ((unsigned)(d & (BIN_NODES - 1)) << 24) | (unsigned)s;
    }
    __syncthreads();
    for (int i = tid; i < ne; i += 256) {
      uint32_t en = stage[i];
      // binary search: largest b with base[b] <= i  (= owning non-empty bin)
      int b = 0;
#pragma unroll
      for (int step = 256; step; step >>= 1) {
        int nb = b + step;
        if (nb < 512 && base[nb] <= i) b = nb;
      }
      int gi = gbase[b] + (i - base[b]);
      if (gi < CAPB) binbuf[(size_t)b * CAPB + gi] = en;
    }
  } else {
    // ---- gemm1 (unscaled, self-converted W1 fragments) ----
    us* As = (us*)smem;                              // 32*136 us = 8704 B
    int wave = tid >> 6, lane = tid & 63;
    int n0 = wave * 32;
    int nn = n0 + (lane & 31);
    int khalf = (lane >> 5) * 8;
    int m = lane & 31;

    short8 bh[8], bl[8];
#pragma unroll
    for (int c = 0; c < 8; ++c) {
#pragma unroll
      for (int j = 0; j < 8; ++j) {
        us h, l;
        split2(W1[(size_t)(c * 16 + khalf + j) * 128 + nn], h, l);
        bh[c][j] = (short)h;
        bl[c][j] = (short)l;
      }
    }

    int t0 = gb - PBLK - ablocks;
    for (int t = t0; t < ntiles; t += G1GRID) {
      int row0 = t * 32;
      __syncthreads();
      for (int j = tid; j < 1024; j += 256) {
        int r = j >> 5, c = j & 31;
        int row = row0 + r;
        float4 v = make_float4(0.f, 0.f, 0.f, 0.f);
        if (row < N) v = *(const float4*)&A[(size_t)row * 128 + c * 4];
        *(ushort4*)&As[r * 136 + c * 4] = make_ushort4(
            f32_to_bf16_rne(v.x), f32_to_bf16_rne(v.y),
            f32_to_bf16_rne(v.z), f32_to_bf16_rne(v.w));
      }
      __syncthreads();

      f32x16 acc = {};
#pragma unroll
      for (int c = 0; c < 8; ++c) {
        short8 ah = *(const short8*)&As[m * 136 + c * 16 + khalf];
        acc = __builtin_amdgcn_mfma_f32_32x32x16_bf16(ah, bh[c], acc, 0, 0, 0);
        acc = __builtin_amdgcn_mfma_f32_32x32x16_bf16(ah, bl[c], acc, 0, 0, 0);
      }

      int colo = n0 + (lane & 31);
      int rbase = row0 + 4 * (lane >> 5);
#pragma unroll
      for (int reg = 0; reg < 16; ++reg) {
        int row = rbase + (reg & 3) + 8 * (reg >> 2);
        if (row < N)
          out_bf16[(size_t)row * 128 + colo] = f32_to_bf16_rne(acc[reg]);
      }
    }
  }
}

// ---------------- pass B: per-bin deg/dis/start + col fill from packed entries ----------------
__global__ __launch_bounds__(256) void k_passB(
    const uint32_t* __restrict__ binbuf, const int* __restrict__ gcur,
    int* __restrict__ deg, float* __restrict__ dis, int* __restrict__ start,
    int* __restrict__ col, int N, int nbins) {
  __shared__ int hist[256], lstart[256], cur[256];
  __shared__ int colstage[CAPB];                     // 24 KB
  __shared__ int binbase_s;
  int b = blockIdx.x, tid = threadIdx.x;
  int node0 = b << BIN_SHIFT;
  int cnt = min(gcur[b], CAPB);
  hist[tid] = 0;
  __syncthreads();
  const uint32_t* bp = binbuf + (size_t)b * CAPB;
  for (int i = tid; i < cnt; i += 256) atomicAdd(&hist[bp[i] >> 24], 1);
  __syncthreads();
  if (tid < 64) {
    // binbase = sum of capped counts of previous bins
    int s = 0;
    for (int i = tid; i < b; i += 64) s += min(gcur[i], CAPB);
#pragma unroll
    for (int off = 32; off; off >>= 1) s += __shfl_xor(s, off, 64);
    if (tid == 0) binbase_s = s;
    // exclusive scan hist[256] -> lstart (4 chunks of 64)
    int carry = 0;
#pragma unroll
    for (int c = 0; c < 4; ++c) {
      int v = hist[c * 64 + tid];
      int incl = v;
#pragma unroll
      for (int off = 1; off < 64; off <<= 1) {
        int t = __shfl_up(incl, off, 64);
        if (tid >= off) incl += t;
      }
      lstart[c * 64 + tid] = carry + incl - v;
      carry += __shfl(incl, 63, 64);
    }
  }
  __syncthreads();
  int binbase = binbase_s;
  {
    int node = node0 + tid;
    if (node < N) {
      int dg = hist[tid];
      deg[node] = dg;
      dis[node] = rsqrtf((float)(dg + 1));
      start[node] = binbase + lstart[tid];
    }
  }
  cur[tid] = lstart[tid];
  __syncthreads();
  for (int i = tid; i < cnt; i += 256) {
    uint32_t en = bp[i];
    int p = atomicAdd(&cur[en >> 24], 1);
    colstage[p] = (int)(en & 0xFFFFFFu);
  }
  __syncthreads();
  for (int i = tid; i < cnt; i += 256) col[binbase + i] = colstage[i];
}

// ---------------- gather layer 1: dis-weighted (h is UNSCALED x@W1) ----------------------------
// acc = sum_e dis[src_e]*h[src_e] + dis[node]*h[node];  act = relu(acc*dis[node] + b1).
// dis[col] preloaded per-lane alongside col; both broadcast via readlane.
__global__ __launch_bounds__(512) void k_gather1(
    const us* __restrict__ h, us* __restrict__ o,
    const int* __restrict__ start, const int* __restrict__ deg,
    const int* __restrict__ col, const float* __restrict__ dis,
    const float* __restrict__ bias, int N) {
  int wave = threadIdx.x >> 6, lane = threadIdx.x & 63;
  int node = blockIdx.x * 8 + wave;
  if (node >= N) return;
  const uint32_t* h1 = (const uint32_t*)h;
  float sc = dis[node];
  uint32_t u = h1[(size_t)node * 64 + lane];     // self row
  float a0 = sc * bflo(u), b0 = sc * bfhi(u);
  float a1 = 0.f, b1 = 0.f, a2 = 0.f, b2 = 0.f, a3 = 0.f, b3 = 0.f;
  float a4 = 0.f, b4 = 0.f, a5 = 0.f, b5 = 0.f, a6 = 0.f, b6 = 0.f, a7 = 0.f, b7 = 0.f;
  int e0 = start[node];
  int dg = deg[node];
  int myc = (lane < dg) ? col[e0 + lane] : N;    // N = zero row (dummy)
  float myd = (lane < dg) ? dis[myc] : 0.f;
  int dgm = min(dg, 64);
  for (int k = 0; k < dgm; k += 8) {
    int c0 = __builtin_amdgcn_readlane(myc, k);
    int c1 = __builtin_amdgcn_readlane(myc, k + 1);
    int c2 = __builtin_amdgcn_readlane(myc, k + 2);
    int c3 = __builtin_amdgcn_readlane(myc, k + 3);
    int c4 = __builtin_amdgcn_readlane(myc, k + 4);
    int c5 = __builtin_amdgcn_readlane(myc, k + 5);
    int c6 = __builtin_amdgcn_readlane(myc, k + 6);
    int c7 = __builtin_amdgcn_readlane(myc, k + 7);
    float d0 = rdlane_f(myd, k),     d1 = rdlane_f(myd, k + 1);
    float d2 = rdlane_f(myd, k + 2), d3 = rdlane_f(myd, k + 3);
    float d4 = rdlane_f(myd, k + 4), d5 = rdlane_f(myd, k + 5);
    float d6 = rdlane_f(myd, k + 6), d7 = rdlane_f(myd, k + 7);
    uint32_t u0 = h1[(size_t)c0 * 64 + lane];
    uint32_t u1 = h1[(size_t)c1 * 64 + lane];
    uint32_t u2 = h1[(size_t)c2 * 64 + lane];
    uint32_t u3 = h1[(size_t)c3 * 64 + lane];
    uint32_t u4 = h1[(size_t)c4 * 64 + lane];
    uint32_t u5 = h1[(size_t)c5 * 64 + lane];
    uint32_t u6 = h1[(size_t)c6 * 64 + lane];
    uint32_t u7 = h1[(size_t)c7 * 64 + lane];
    a0 += d0 * bflo(u0); b0 += d0 * bfhi(u0);
    a1 += d1 * bflo(u1); b1 += d1 * bfhi(u1);
    a2 += d2 * bflo(u2); b2 += d2 * bfhi(u2);
    a3 += d3 * bflo(u3); b3 += d3 * bfhi(u3);
    a4 += d4 * bflo(u4); b4 += d4 * bfhi(u4);
    a5 += d5 * bflo(u5); b5 += d5 * bfhi(u5);
    a6 += d6 * bflo(u6); b6 += d6 * bfhi(u6);
    a7 += d7 * bflo(u7); b7 += d7 * bfhi(u7);
  }
  // extremely rare deg > 64 fallback (Poisson mean 16)
  for (int e = e0 + 64; e < e0 + dg; ++e) {
    int c = col[e];
    float dd = dis[c];
    uint32_t u0 = h1[(size_t)c * 64 + lane];
    a0 += dd * bflo(u0); b0 += dd * bfhi(u0);
  }
  float2 bb = ((const float2*)bias)[lane];
  float ax = ((a0 + a1) + (a2 + a3)) + ((a4 + a5) + (a6 + a7));
  float ay = ((b0 + b1) + (b2 + b3)) + ((b4 + b5) + (b6 + b7));
  float rx = fmaxf(ax * sc + bb.x, 0.f);
  float ry = fmaxf(ay * sc + bb.y, 0.f);
  ((uint32_t*)o)[(size_t)node * 64 + lane] =
      ((uint32_t)f32_to_bf16_rne(ry) << 16) | f32_to_bf16_rne(rx);
}

// ---------------- layer-2 GEMM: hbuf[row][128] = rne_bf16(dis[row] * (act @ W2)) ----------------
__global__ __launch_bounds__(256) void k_gemm2(
    const us* __restrict__ A, const us* __restrict__ Wh,
    const us* __restrict__ Wl, const float* __restrict__ dis,
    us* __restrict__ out_bf16, int N, int ntiles) {
  __shared__ us As[32 * 136];
  int tid = threadIdx.x;
  int wave = tid >> 6, lane = tid & 63;
  int n0 = wave * 32;
  int nn = n0 + (lane & 31);
  int khalf = (lane >> 5) * 8;
  int m = lane & 31;

  short8 bh[8], bl[8];
#pragma unroll
  for (int c = 0; c < 8; ++c) {
    bh[c] = *(const short8*)&Wh[nn * 128 + c * 16 + khalf];
    bl[c] = *(const short8*)&Wl[nn * 128 + c * 16 + khalf];
  }

  for (int t = blockIdx.x; t < ntiles; t += gridDim.x) {
    int row0 = t * 32;
    __syncthreads();
    for (int j = tid; j < 512; j += 256) {
      int r = j >> 4, c = j & 15;
      int row = row0 + r;
      uint4 v = make_uint4(0u, 0u, 0u, 0u);
      if (row < N) v = *(const uint4*)&A[(size_t)row * 128 + c * 8];
      *(uint4*)&As[r * 136 + c * 8] = v;
    }
    __syncthreads();

    f32x16 acc = {};
#pragma unroll
    for (int c = 0; c < 8; ++c) {
      short8 ah = *(const short8*)&As[m * 136 + c * 16 + khalf];
      acc = __builtin_amdgcn_mfma_f32_32x32x16_bf16(ah, bh[c], acc, 0, 0, 0);
      acc = __builtin_amdgcn_mfma_f32_32x32x16_bf16(ah, bl[c], acc, 0, 0, 0);
    }

    int col = n0 + (lane & 31);
    int rbase = row0 + 4 * (lane >> 5);
#pragma unroll
    for (int reg = 0; reg < 16; ++reg) {
      int row = rbase + (reg & 3) + 8 * (reg >> 2);
      if (row < N) {
        float v = acc[reg] * dis[row];
        out_bf16[(size_t)row * 128 + col] = f32_to_bf16_rne(v);
      }
    }
  }
}

// ---------------- gather layer 2: h pre-scaled by dis[src] (unchanged champion path) -----------
__global__ __launch_bounds__(512) void k_gather(
    const us* __restrict__ h, us* __restrict__ o,
    const int* __restrict__ start, const int* __restrict__ deg,
    const int* __restrict__ col, const float* __restrict__ dis,
    const float* __restrict__ bias, int N) {
  int wave = threadIdx.x >> 6, lane = threadIdx.x & 63;
  int node = blockIdx.x * 8 + wave;
  if (node >= N) return;
  const uint32_t* h1 = (const uint32_t*)h;
  uint32_t u = h1[(size_t)node * 64 + lane];     // self row
  float a0 = bflo(u), b0 = bfhi(u);
  float a1 = 0.f, b1 = 0.f, a2 = 0.f, b2 = 0.f, a3 = 0.f, b3 = 0.f;
  float a4 = 0.f, b4 = 0.f, a5 = 0.f, b5 = 0.f, a6 = 0.f, b6 = 0.f, a7 = 0.f, b7 = 0.f;
  int e0 = start[node];
  int dg = deg[node];
  int myc = (lane < dg) ? col[e0 + lane] : N;    // N = zero row (dummy)
  int dgm = min(dg, 64);
  for (int k = 0; k < dgm; k += 8) {
    int c0 = __builtin_amdgcn_readlane(myc, k);
    int c1 = __builtin_amdgcn_readlane(myc, k + 1);
    int c2 = __builtin_amdgcn_readlane(myc, k + 2);
    int c3 = __builtin_amdgcn_readlane(myc, k + 3);
    int c4 = __builtin_amdgcn_readlane(myc, k + 4);
    int c5 = __builtin_amdgcn_readlane(myc, k + 5);
    int c6 = __builtin_amdgcn_readlane(myc, k + 6);
    int c7 = __builtin_amdgcn_readlane(myc, k + 7);
    uint32_t u0 = h1[(size_t)c0 * 64 + lane];
    uint32_t u1 = h1[(size_t)c1 * 64 + lane];
    uint32_t u2 = h1[(size_t)c2 * 64 + lane];
    uint32_t u3 = h1[(size_t)c3 * 64 + lane];
    uint32_t u4 = h1[(size_t)c4 * 64 + lane];
    uint32_t u5 = h1[(size_t)c5 * 64 + lane];
    uint32_t u6 = h1[(size_t)c6 * 64 + lane];
    uint32_t u7 = h1[(size_t)c7 * 64 + lane];
    a0 += bflo(u0); b0 += bfhi(u0);
    a1 += bflo(u1); b1 += bfhi(u1);
    a2 += bflo(u2); b2 += bfhi(u2);
    a3 += bflo(u3); b3 += bfhi(u3);
    a4 += bflo(u4); b4 += bfhi(u4);
    a5 += bflo(u5); b5 += bfhi(u5);
    a6 += bflo(u6); b6 += bfhi(u6);
    a7 += bflo(u7); b7 += bfhi(u7);
  }
  // extremely rare deg > 64 fallback (Poisson mean 16)
  for (int e = e0 + 64; e < e0 + dg; ++e) {
    uint32_t u0 = h1[(size_t)col[e] * 64 + lane];
    a0 += bflo(u0); b0 += bfhi(u0);
  }
  float sc = dis[node];
  float2 bb = ((const float2*)bias)[lane];
  float ax = ((a0 + a1) + (a2 + a3)) + ((a4 + a5) + (a6 + a7));
  float ay = ((b0 + b1) + (b2 + b3)) + ((b4 + b5) + (b6 + b7));
  float rx = fmaxf(ax * sc + bb.x, 0.f);
  float ry = fmaxf(ay * sc + bb.y, 0.f);
  ((uint32_t*)o)[(size_t)node * 64 + lane] =
      ((uint32_t)f32_to_bf16_rne(ry) << 16) | f32_to_bf16_rne(rx);
}

// ---------------- head: out = log_softmax(act @ Wc + bc) via MFMA, fused softmax ----------------
__global__ __launch_bounds__(256) void k_head_mfma(
    const us* __restrict__ act, const us* __restrict__ Wch,
    const us* __restrict__ Wcl, const float* __restrict__ bc,
    float* __restrict__ out, int N) {
  __shared__ us As[64 * 136];
  __shared__ float red[2][2][64];
  int tid = threadIdx.x;
  int wave = tid >> 6, lane = tid & 63;
  int rt = wave >> 1, ct = wave & 1;
  int colj = ct * 32 + (lane & 31);
  int khalf = (lane >> 5) * 8;
  int m = lane & 31;

  short8 bh[8], bl[8];
#pragma unroll
  for (int c = 0; c < 8; ++c) {
    bh[c] = *(const short8*)&Wch[colj * 128 + c * 16 + khalf];
    bl[c] = *(const short8*)&Wcl[colj * 128 + c * 16 + khalf];
  }

  int row0 = blockIdx.x * 64;
  for (int j = tid; j < 1024; j += 256) {
    int r = j >> 4, c = j & 15;
    int row = row0 + r;
    uint4 v = make_uint4(0u, 0u, 0u, 0u);
    if (row < N) v = *(const uint4*)&act[(size_t)row * 128 + c * 8];
    *(uint4*)&As[r * 136 + c * 8] = v;
  }
  __syncthreads();

  f32x16 acc = {};
  int mrow = rt * 32 + m;
#pragma unroll
  for (int c = 0; c < 8; ++c) {
    short8 ah = *(const short8*)&As[mrow * 136 + c * 16 + khalf];
    acc = __builtin_amdgcn_mfma_f32_32x32x16_bf16(ah, bh[c], acc, 0, 0, 0);
    acc = __builtin_amdgcn_mfma_f32_32x32x16_bf16(ah, bl[c], acc, 0, 0, 0);
  }

  float bcv = bc[colj];
  float lg[16], mx[16];
#pragma unroll
  for (int reg = 0; reg < 16; ++reg) {
    lg[reg] = acc[reg] + bcv;
    float v = lg[reg];
#pragma unroll
    for (int off = 16; off > 0; off >>= 1) v = fmaxf(v, __shfl_xor(v, off, 32));
    mx[reg] = v;
  }
  if ((lane & 31) == 0) {
#pragma unroll
    for (int reg = 0; reg < 16; ++reg) {
      int rl = rt * 32 + (reg & 3) + 8 * (reg >> 2) + 4 * (lane >> 5);
      red[0][ct][rl] = mx[reg];
    }
  }
  __syncthreads();

  float ex[16], sm[16];
#pragma unroll
  for (int reg = 0; reg < 16; ++reg) {
    int rl = rt * 32 + (reg & 3) + 8 * (reg >> 2) + 4 * (lane >> 5);
    float rmax = fmaxf(red[0][0][rl], red[0][1][rl]);
    ex[reg] = lg[reg] - rmax;
    float v = expf(ex[reg]);
#pragma unroll
    for (int off = 16; off > 0; off >>= 1) v += __shfl_xor(v, off, 32);
    sm[reg] = v;
  }
  if ((lane & 31) == 0) {
#pragma unroll
    for (int reg = 0; reg < 16; ++reg) {
      int rl = rt * 32 + (reg & 3) + 8 * (reg >> 2) + 4 * (lane >> 5);
      red[1][ct][rl] = sm[reg];
    }
  }
  __syncthreads();

#pragma unroll
  for (int reg = 0; reg < 16; ++reg) {
    int rl = rt * 32 + (reg & 3) + 8 * (reg >> 2) + 4 * (lane >> 5);
    int row = row0 + rl;
    if (row < N) {
      float total = red[1][0][rl] + red[1][1][rl];
      out[(size_t)row * 64 + colj] = ex[reg] - logf(total);
    }
  }
}

extern "C" void kernel_launch(void* const* d_in, const int* in_sizes, int n_in,
                              void* d_out, int out_size, void* d_ws, size_t ws_size,
                              hipStream_t stream) {
  const float* x   = (const float*)d_in[0];
  const int*   ei  = (const int*)d_in[1];
  const float* W1  = (const float*)d_in[2];
  const float* b1  = (const float*)d_in[3];
  const float* W2  = (const float*)d_in[4];
  const float* b2  = (const float*)d_in[5];
  const float* Wp1 = (const float*)d_in[6];
  const float* bp1 = (const float*)d_in[7];
  const float* Wp2 = (const float*)d_in[8];
  const float* bp2 = (const float*)d_in[9];
  float* out = (float*)d_out;

  int N = in_sizes[0] / 128;
  int E = in_sizes[1] / 2;
  const int* src = ei;
  const int* dst = ei + E;
  int nbins = (N + BIN_NODES - 1) >> BIN_SHIFT;

  // workspace layout (int granularity)
  float* dis   = (float*)d_ws;                    // N
  int*   deg   = (int*)(dis + N);                 // N
  int*   start = deg + N;                         // N
  int*   col   = start + N;                       // E
  int*   gcur  = col + ((E + 3) & ~3);            // 512 (zeroed by memset)
  us* Wt2h = (us*)(gcur + 512);                   // 16384 each
  us* Wt2l = Wt2h + 16384;
  us* Wch  = Wt2l + 16384;                        // 8192
  us* Wcl  = Wch + 8192;                          // 8192
  float* bc = (float*)(Wcl + 8192);               // 64 (+pad)
  uint32_t* binbuf = (uint32_t*)(bc + 80);        // nbins*CAPB packed u32 (~9.6 MB)
  us* hbuf = (us*)(binbuf + (size_t)nbins * CAPB);  // (N+1)*128 bf16 (row N = zero, by k_bg)
  us* act  = hbuf + (size_t)(N + 1) * 128;          // N*128 bf16 = 25.6 MB

  hipMemsetAsync(gcur, 0, 512 * sizeof(int), stream);

  int ablocks = (E + EPB - 1) / EPB;
  int ntiles = (N + 31) / 32;
  int agblocks = (N + 7) / 8;
  int hblocks = (N + 63) / 64;

  // mega-dispatch: prep ∥ binA ∥ gemm1 (x @ W1, self-converted W1 fragments)
  k_bg<<<PBLK + ablocks + G1GRID, 256, 0, stream>>>(
      src, dst, binbuf, gcur, E, nbins, ablocks,
      x, W1, hbuf, N, ntiles,
      W2, Wp1, Wp2, bp1, bp2,
      Wt2h, Wt2l, Wch, Wcl, bc, (int*)(hbuf + (size_t)N * 128));
  k_passB<<<nbins, 256, 0, stream>>>(binbuf, gcur, deg, dis, start, col, N, nbins);

  // layer 1 aggregate (dis-weighted, since hbuf is unscaled)
  k_gather1<<<agblocks, 512, 0, stream>>>(hbuf, act, start, deg, col, dis, b1, N);
  // layer 2
  k_gemm2<<<ntiles < 1024 ? ntiles : 1024, 256, 0, stream>>>(act, Wt2h, Wt2l, dis, hbuf, N, ntiles);
  k_gather<<<agblocks, 512, 0, stream>>>(hbuf, act, start, deg, col, dis, b2, N);
  // folded head (MFMA + fused log_softmax)
  k_head_mfma<<<hblocks, 256, 0, stream>>>(act, Wch, Wcl, bc, out, N);
}